// Round 4
// baseline (175.608 us; speedup 1.0000x reference)
//
#include <hip/hip_runtime.h>
#include <hip/hip_bf16.h>

typedef short bf16x8 __attribute__((ext_vector_type(8)));
typedef float f32x4 __attribute__((ext_vector_type(4)));
typedef unsigned short u16x4 __attribute__((ext_vector_type(4)));
typedef unsigned short u16;

#define NB2 (-0.35f * 1.44269504088896340736f)

__device__ __forceinline__ u16 f2bf(float f) {
  union { float f; unsigned int u; } v; v.f = f;
  unsigned int x = v.u;
  return (u16)((x + 0x7FFFu + ((x >> 16) & 1u)) >> 16);
}

#define GLOAD_LDS(g, l) __builtin_amdgcn_global_load_lds( \
    (const __attribute__((address_space(1))) unsigned int*)(g), \
    (__attribute__((address_space(3))) unsigned int*)(l), 16, 0, 0)

// ---------- preprocessing: centers -> bf16 + csq ----------
__global__ __launch_bounds__(128)
void prep_cen(const float* __restrict__ cen, u16* __restrict__ cbf,
              float* __restrict__ csq) {
  const int row = blockIdx.x, t = threadIdx.x;
  float4 v = ((const float4*)(cen + (size_t)row * 512))[t];
  u16x4 h; h[0] = f2bf(v.x); h[1] = f2bf(v.y); h[2] = f2bf(v.z); h[3] = f2bf(v.w);
  *(u16x4*)&cbf[(size_t)row * 512 + t * 4] = h;
  float ss = v.x * v.x + v.y * v.y + v.z * v.z + v.w * v.w;
  ss += __shfl_xor(ss, 1);  ss += __shfl_xor(ss, 2);
  ss += __shfl_xor(ss, 4);  ss += __shfl_xor(ss, 8);
  ss += __shfl_xor(ss, 16); ss += __shfl_xor(ss, 32);
  __shared__ float r2[2];
  if ((t & 63) == 0) r2[t >> 6] = ss;
  __syncthreads();
  if (t == 0) csq[row] = r2[0] + r2[1];
}

// ---------- preprocessing: W [4096][128] f32 -> Wt [128][4096] bf16 ----------
__global__ __launch_bounds__(256)
void prep_w(const float* __restrict__ W, u16* __restrict__ wt) {
  __shared__ u16 t_[128 * 66];
  const int c0 = blockIdx.x * 64;
  const int t = threadIdx.x;
#pragma unroll
  for (int it = 0; it < 32; ++it) {
    int idx = it * 256 + t;
    int cl = idx >> 7;
    int o  = idx & 127;
    t_[o * 66 + cl] = f2bf(W[(size_t)(c0 + cl) * 128 + o]);
  }
  __syncthreads();
#pragma unroll
  for (int it = 0; it < 8; ++it) {
    int idx = it * 256 + t;
    int o  = idx >> 4;
    int cq = idx & 15;
    u16x4 h;
    h[0] = t_[o * 66 + cq * 4 + 0]; h[1] = t_[o * 66 + cq * 4 + 1];
    h[2] = t_[o * 66 + cq * 4 + 2]; h[3] = t_[o * 66 + cq * 4 + 3];
    *(u16x4*)&wt[(size_t)o * 4096 + c0 + cq * 4] = h;
  }
}

// ---------- init: out = bias ----------
__global__ __launch_bounds__(256)
void init_out(const float* __restrict__ bias, float* __restrict__ out) {
  const int i4 = blockIdx.x * 256 + threadIdx.x;      // 0..524287 float4s
  float4 b = ((const float4*)bias)[i4 & 31];
  ((float4*)out)[i4] = b;
}

// ---------- main fused kernel: 512 blocks = 256 row-tiles x 2 center-halves ----------
__global__ __launch_bounds__(512, 2)
void rbf_main(const float* __restrict__ x, const u16* __restrict__ cbf,
              const u16* __restrict__ wtg, const float* __restrict__ csq,
              float* __restrict__ out)
{
  __shared__ u16 cs[4][4096];   // centers K-step buffers (64 c x 64 k), 32 KB
  __shared__ u16 wt[2][8192];   // W chunk [128 o][64 c] dbuf, 32 KB
  __shared__ u16 pl[4096];      // P tile [64 m][64 c], 8 KB
  __shared__ float xsq_s[64];

  const int tid = threadIdx.x;
  const int lane = tid & 63;
  const int wv = tid >> 6;
  const int mw = wv >> 1;          // m-tile 0..3
  const int cw = wv & 1;           // center half-of-chunk / o half
  const int l15 = lane & 15;
  const int lg = lane >> 4;
  const int bid = blockIdx.x;
  const int chalf = bid & 1;                    // which 2048-center half
  const size_t r0 = (size_t)(bid >> 1) * 64;    // row-tile
  const size_t cbase = (size_t)chalf * (2048 * 512);
  const int ch2048 = chalf * 2048;

  // staging per-thread offsets (pre-swizzled global source, linear LDS dest)
  const int scr = tid >> 3;
  const int sgk = tid & 7;
  const int cen_off = scr * 512 + ((sgk ^ (scr & 7)) * 8);
  const int wt_off  = scr * 4096 + ((sgk ^ (scr & 7)) * 8);
  u16* const cs_dst = ((u16*)cs) + tid * 8;
  u16* const wt_dst = ((u16*)wt) + tid * 8;

#define STAGE_CS(ccn, kkn, slot) \
  GLOAD_LDS(cbf + cbase + (ccn) * 32768 + (kkn) * 64 + cen_off, cs_dst + (slot) * 4096)
#define STAGE_W(ccn, slot) do { \
  GLOAD_LDS(wtg + wt_off + ch2048 + (ccn) * 64,          wt_dst + (slot) * 8192);        \
  GLOAD_LDS(wtg + wt_off + 262144 + ch2048 + (ccn) * 64, wt_dst + (slot) * 8192 + 4096); \
} while (0)

  // prologue: stage cs(0), W(0), cs(1), cs(2)
  STAGE_CS(0, 0, 0);
  STAGE_W(0, 0);
  STAGE_CS(0, 1, 1);
  STAGE_CS(0, 2, 2);

  // ---- x fragments -> registers + row sums of squares ----
  bf16x8 xf[16];
  {
    const float* xr = x + (r0 + mw * 16 + l15) * 512 + lg * 8;
    float ss = 0.f;
#pragma unroll
    for (int g = 0; g < 4; ++g) {
#pragma unroll
      for (int q = 0; q < 4; ++q) {
        const int f = g * 4 + q;
        float4 a = *(const float4*)(xr + f * 32);
        float4 b = *(const float4*)(xr + f * 32 + 4);
        ss += a.x * a.x + a.y * a.y + a.z * a.z + a.w * a.w
            + b.x * b.x + b.y * b.y + b.z * b.z + b.w * b.w;
        bf16x8 h;
        h[0] = (short)f2bf(a.x); h[1] = (short)f2bf(a.y);
        h[2] = (short)f2bf(a.z); h[3] = (short)f2bf(a.w);
        h[4] = (short)f2bf(b.x); h[5] = (short)f2bf(b.y);
        h[6] = (short)f2bf(b.z); h[7] = (short)f2bf(b.w);
        xf[f] = h;
      }
      __builtin_amdgcn_sched_barrier(0);
    }
    ss += __shfl_xor(ss, 16);
    ss += __shfl_xor(ss, 32);
    if (lg == 0) xsq_s[mw * 16 + l15] = ss;
  }
  asm volatile("s_waitcnt lgkmcnt(0)" ::: "memory");
  __builtin_amdgcn_s_barrier();
  float xq[4];
#pragma unroll
  for (int r = 0; r < 4; ++r) xq[r] = xsq_s[mw * 16 + lg * 4 + r];

  float cq0 = csq[ch2048 + cw * 32 + l15];
  float cq1 = csq[ch2048 + cw * 32 + 16 + l15];

  // LDS read offsets (element units, swizzled)
  int bo[2][2], wo[2][4], po[2];
#pragma unroll
  for (int ks = 0; ks < 2; ++ks) {
    const int kb = ks * 32 + lg * 8;
#pragma unroll
    for (int ct = 0; ct < 2; ++ct) {
      const int cr = cw * 32 + ct * 16 + l15;
      bo[ks][ct] = cr * 64 + (kb ^ ((cr & 7) << 3));
    }
#pragma unroll
    for (int ot = 0; ot < 4; ++ot) {
      const int o = cw * 64 + ot * 16 + l15;
      wo[ks][ot] = o * 64 + (kb ^ ((o & 7) << 3));
    }
    const int am = mw * 16 + l15;
    po[ks] = am * 64 + (kb ^ ((am & 7) << 3));
  }

  const f32x4 z4 = {0.f, 0.f, 0.f, 0.f};
  f32x4 s0 = z4, s1 = z4;
  f32x4 oa[4] = {z4, z4, z4, z4};

#define KSTEP(cc, p, VM, DO_CS, DO_W) do { \
    asm volatile("s_waitcnt vmcnt(" #VM ")" ::: "memory"); \
    __builtin_amdgcn_s_barrier(); \
    __builtin_amdgcn_sched_barrier(0); \
    const u16* csb = &cs[(p) & 3][0]; \
    bf16x8 b00 = *(const bf16x8*)(csb + bo[0][0]); \
    bf16x8 b01 = *(const bf16x8*)(csb + bo[0][1]); \
    bf16x8 b10 = *(const bf16x8*)(csb + bo[1][0]); \
    bf16x8 b11 = *(const bf16x8*)(csb + bo[1][1]); \
    if (DO_CS) { STAGE_CS((cc) + (((p) + 3) >> 3), ((p) + 3) & 7, ((p) + 3) & 3); } \
    if (DO_W)  { STAGE_W((cc) + 1, ((cc) + 1) & 1); } \
    __builtin_amdgcn_s_setprio(1); \
    s0 = __builtin_amdgcn_mfma_f32_16x16x32_bf16(xf[2 * (p)],     b00, s0, 0, 0, 0); \
    s1 = __builtin_amdgcn_mfma_f32_16x16x32_bf16(xf[2 * (p)],     b01, s1, 0, 0, 0); \
    s0 = __builtin_amdgcn_mfma_f32_16x16x32_bf16(xf[2 * (p) + 1], b10, s0, 0, 0, 0); \
    s1 = __builtin_amdgcn_mfma_f32_16x16x32_bf16(xf[2 * (p) + 1], b11, s1, 0, 0, 0); \
    __builtin_amdgcn_s_setprio(0); \
  } while (0)

#define CHUNK_TAIL(cc) do { \
    const int c0l = cw * 32 + l15; \
    _Pragma("unroll") \
    for (int r = 0; r < 4; ++r) { \
      const int m = mw * 16 + lg * 4 + r; \
      const int sw = (m & 7) << 3; \
      float v0 = __builtin_amdgcn_exp2f(NB2 * (xq[r] + cq0 - 2.f * s0[r])); \
      float v1 = __builtin_amdgcn_exp2f(NB2 * (xq[r] + cq1 - 2.f * s1[r])); \
      pl[m * 64 + (c0l ^ sw)]        = f2bf(v0); \
      pl[m * 64 + ((c0l + 16) ^ sw)] = f2bf(v1); \
    } \
    s0 = z4; s1 = z4; \
    { const int nc = (cc) < 31 ? (cc) + 1 : 31; \
      cq0 = csq[ch2048 + nc * 64 + cw * 32 + l15]; \
      cq1 = csq[ch2048 + nc * 64 + cw * 32 + 16 + l15]; } \
    asm volatile("s_waitcnt lgkmcnt(0)" ::: "memory"); \
    __builtin_amdgcn_s_barrier(); \
    __builtin_amdgcn_sched_barrier(0); \
    const u16* wtb_ = &wt[(cc) & 1][0]; \
    _Pragma("unroll") \
    for (int ks = 0; ks < 2; ++ks) { \
      bf16x8 pa = *(const bf16x8*)(pl + po[ks]); \
      _Pragma("unroll") \
      for (int ot = 0; ot < 4; ++ot) { \
        bf16x8 wb = *(const bf16x8*)(wtb_ + wo[ks][ot]); \
        oa[ot] = __builtin_amdgcn_mfma_f32_16x16x32_bf16(pa, wb, oa[ot], 0, 0, 0); \
      } \
    } \
  } while (0)

  for (int cc = 0; cc < 31; ++cc) {
    KSTEP(cc, 0, 2, 1, 0);
    KSTEP(cc, 1, 2, 1, 0);
    KSTEP(cc, 2, 2, 1, 0);
    KSTEP(cc, 3, 2, 1, 0);
    KSTEP(cc, 4, 2, 1, 0);
    KSTEP(cc, 5, 2, 1, 1);
    KSTEP(cc, 6, 4, 1, 0);
    KSTEP(cc, 7, 4, 1, 0);
    CHUNK_TAIL(cc);
  }
  KSTEP(31, 0, 2, 1, 0);
  KSTEP(31, 1, 2, 1, 0);
  KSTEP(31, 2, 2, 1, 0);
  KSTEP(31, 3, 2, 1, 0);
  KSTEP(31, 4, 2, 1, 0);
  KSTEP(31, 5, 2, 0, 0);
  KSTEP(31, 6, 1, 0, 0);
  KSTEP(31, 7, 0, 0, 0);
  CHUNK_TAIL(31);

  // ---- epilogue: out += partial (bias added by init_out) ----
#pragma unroll
  for (int ot = 0; ot < 4; ++ot) {
    const int o = cw * 64 + ot * 16 + l15;
#pragma unroll
    for (int r = 0; r < 4; ++r) {
      const int m = mw * 16 + lg * 4 + r;
      atomicAdd(&out[(r0 + m) * 128 + o], oa[ot][r]);
    }
  }
#undef KSTEP
#undef CHUNK_TAIL
#undef STAGE_CS
#undef STAGE_W
}

extern "C" void kernel_launch(void* const* d_in, const int* in_sizes, int n_in,
                              void* d_out, int out_size, void* d_ws, size_t ws_size,
                              hipStream_t stream) {
  (void)in_sizes; (void)n_in; (void)out_size; (void)ws_size;
  const float* x   = (const float*)d_in[0];
  const float* cen = (const float*)d_in[1];
  const float* W   = (const float*)d_in[2];
  const float* b   = (const float*)d_in[3];
  u16* cbf  = (u16*)d_ws;                    // 4096*512 bf16 = 4 MB
  u16* wtg  = cbf + 4096 * 512;              // 128*4096 bf16 = 1 MB
  float* cs = (float*)(wtg + 128 * 4096);    // 4096 f32 = 16 KB
  prep_cen<<<4096, 128, 0, stream>>>(cen, cbf, cs);
  prep_w<<<64, 256, 0, stream>>>(W, wtg);
  init_out<<<2048, 256, 0, stream>>>(b, (float*)d_out);
  rbf_main<<<512, 512, 0, stream>>>(x, cbf, wtg, cs, (float*)d_out);
}

// Round 5
// 125.109 us; speedup vs baseline: 1.4036x; 1.4036x over previous
//
#include <hip/hip_runtime.h>
#include <hip/hip_bf16.h>

typedef short bf16x8 __attribute__((ext_vector_type(8)));
typedef float f32x4 __attribute__((ext_vector_type(4)));
typedef unsigned short u16x4 __attribute__((ext_vector_type(4)));
typedef unsigned short u16;

#define NB2 (-0.35f * 1.44269504088896340736f)
#define MFMA16(a, b, c) __builtin_amdgcn_mfma_f32_16x16x32_bf16(a, b, c, 0, 0, 0)

__device__ __forceinline__ u16 f2bf(float f) {
  union { float f; unsigned int u; } v; v.f = f;
  unsigned int x = v.u;
  return (u16)((x + 0x7FFFu + ((x >> 16) & 1u)) >> 16);
}

#define GLOAD_LDS(g, l) __builtin_amdgcn_global_load_lds( \
    (const __attribute__((address_space(1))) unsigned int*)(g), \
    (__attribute__((address_space(3))) unsigned int*)(l), 16, 0, 0)

// ---------- preprocessing: centers -> bf16 + csq ----------
__global__ __launch_bounds__(128)
void prep_cen(const float* __restrict__ cen, u16* __restrict__ cbf,
              float* __restrict__ csq) {
  const int row = blockIdx.x, t = threadIdx.x;
  float4 v = ((const float4*)(cen + (size_t)row * 512))[t];
  u16x4 h; h[0] = f2bf(v.x); h[1] = f2bf(v.y); h[2] = f2bf(v.z); h[3] = f2bf(v.w);
  *(u16x4*)&cbf[(size_t)row * 512 + t * 4] = h;
  float ss = v.x * v.x + v.y * v.y + v.z * v.z + v.w * v.w;
  ss += __shfl_xor(ss, 1);  ss += __shfl_xor(ss, 2);
  ss += __shfl_xor(ss, 4);  ss += __shfl_xor(ss, 8);
  ss += __shfl_xor(ss, 16); ss += __shfl_xor(ss, 32);
  __shared__ float r2[2];
  if ((t & 63) == 0) r2[t >> 6] = ss;
  __syncthreads();
  if (t == 0) csq[row] = r2[0] + r2[1];
}

// ---------- preprocessing: W [4096][128] f32 -> Wt [128][4096] bf16 ----------
__global__ __launch_bounds__(256)
void prep_w(const float* __restrict__ W, u16* __restrict__ wt) {
  __shared__ u16 t_[128 * 66];
  const int c0 = blockIdx.x * 64;
  const int t = threadIdx.x;
#pragma unroll
  for (int it = 0; it < 32; ++it) {
    int idx = it * 256 + t;
    int cl = idx >> 7;
    int o  = idx & 127;
    t_[o * 66 + cl] = f2bf(W[(size_t)(c0 + cl) * 128 + o]);
  }
  __syncthreads();
#pragma unroll
  for (int it = 0; it < 8; ++it) {
    int idx = it * 256 + t;
    int o  = idx >> 4;
    int cq = idx & 15;
    u16x4 h;
    h[0] = t_[o * 66 + cq * 4 + 0]; h[1] = t_[o * 66 + cq * 4 + 1];
    h[2] = t_[o * 66 + cq * 4 + 2]; h[3] = t_[o * 66 + cq * 4 + 3];
    *(u16x4*)&wt[(size_t)o * 4096 + c0 + cq * 4] = h;
  }
}

// ---------- init: out = bias ----------
__global__ __launch_bounds__(256)
void init_out(const float* __restrict__ bias, float* __restrict__ out) {
  const int i4 = blockIdx.x * 256 + threadIdx.x;
  float4 b = ((const float4*)bias)[i4 & 31];
  ((float4*)out)[i4] = b;
}

// ---------- main fused kernel: 256 blocks = 128 row-tiles x 2 center-halves ----------
__global__ __launch_bounds__(512, 2)
void rbf_main(const float* __restrict__ x, const u16* __restrict__ cbf,
              const u16* __restrict__ wtg, const float* __restrict__ csq_g,
              float* __restrict__ out)
{
  __shared__ u16 cs[8][4096];    // 8 K-subtile slots (64c x 64k), 64 KB
  __shared__ u16 wt[2][8192];    // W chunk [128o][64c] dbuf, 32 KB
  __shared__ u16 pl[8192];       // P tile [128m][64c], 16 KB
  __shared__ float csq_l[2048];  // all csq for this half, 8 KB
  __shared__ float xsq_s[128];

  const int tid = threadIdx.x;
  const int lane = tid & 63;
  const int mw = tid >> 6;         // wave = m-tile 0..7
  const int l15 = lane & 15;
  const int lg = lane >> 4;
  const int bid = blockIdx.x;
  const int chalf = bid & 1;
  const size_t r0 = (size_t)(bid >> 1) * 128;
  const size_t cbase = (size_t)chalf * (2048 * 512);
  const int ch2048 = chalf * 2048;

  // staging offsets (pre-swizzled global source, linear LDS dest)
  const int scr = tid >> 3;
  const int sgk = tid & 7;
  const int cen_off = scr * 512 + ((sgk ^ (scr & 7)) * 8);
  const int wt_off  = scr * 4096 + ((sgk ^ (scr & 7)) * 8);
  u16* const cs_dst = ((u16*)cs) + tid * 8;
  u16* const wt_dst = ((u16*)wt) + tid * 8;

#define S_CS(ccn, j, slot) \
  GLOAD_LDS(cbf + cbase + (ccn) * 32768 + (j) * 64 + cen_off, cs_dst + (slot) * 4096)
#define S_W(ccn, slot) do { \
  GLOAD_LDS(wtg + ch2048 + (ccn) * 64 + wt_off,          wt_dst + (slot) * 8192); \
  GLOAD_LDS(wtg + 262144 + ch2048 + (ccn) * 64 + wt_off, wt_dst + (slot) * 8192 + 4096); \
} while (0)

  // prologue staging: csq, first 4 K-subtiles of chunk 0, W(0)
  GLOAD_LDS(csq_g + ch2048 + tid * 4, ((float*)csq_l) + tid * 4);
  S_CS(0, 0, 0); S_CS(0, 1, 1); S_CS(0, 2, 2); S_CS(0, 3, 3);
  S_W(0, 0);

  // ---- x fragments -> registers + row sums of squares ----
  bf16x8 xf[16];
  {
    const float* xr = x + (r0 + mw * 16 + l15) * 512 + lg * 8;
    float ss = 0.f;
#pragma unroll
    for (int g = 0; g < 4; ++g) {
#pragma unroll
      for (int q = 0; q < 4; ++q) {
        const int f = g * 4 + q;
        float4 a = *(const float4*)(xr + f * 32);
        float4 b = *(const float4*)(xr + f * 32 + 4);
        ss += a.x * a.x + a.y * a.y + a.z * a.z + a.w * a.w
            + b.x * b.x + b.y * b.y + b.z * b.z + b.w * b.w;
        bf16x8 h;
        h[0] = (short)f2bf(a.x); h[1] = (short)f2bf(a.y);
        h[2] = (short)f2bf(a.z); h[3] = (short)f2bf(a.w);
        h[4] = (short)f2bf(b.x); h[5] = (short)f2bf(b.y);
        h[6] = (short)f2bf(b.z); h[7] = (short)f2bf(b.w);
        xf[f] = h;
      }
      __builtin_amdgcn_sched_barrier(0);
    }
    ss += __shfl_xor(ss, 16);
    ss += __shfl_xor(ss, 32);
    if (lg == 0) xsq_s[mw * 16 + l15] = ss;
  }
  // drain csq DMA (oldest of 7) + xsq writes, then block-wide visibility
  asm volatile("s_waitcnt lgkmcnt(0) vmcnt(6)" ::: "memory");
  __builtin_amdgcn_s_barrier();

  float xq[4];
#pragma unroll
  for (int r = 0; r < 4; ++r) xq[r] = xsq_s[mw * 16 + lg * 4 + r];
  float cq[4];
#pragma unroll
  for (int ct = 0; ct < 4; ++ct) cq[ct] = csq_l[ct * 16 + l15];

  // unified LDS fragment bases (B/W/P share them; +ct*1024 / +ot*1024 immediates)
  const int kswz = (l15 & 7) << 3;
  const int base0 = l15 * 64 + ((lg * 8) ^ kswz);
  const int base1 = l15 * 64 + (((lg * 8) + 32) ^ kswz);

  const f32x4 z4 = {0.f, 0.f, 0.f, 0.f};
  f32x4 sacc[4] = {z4, z4, z4, z4};
  f32x4 oa[8] = {z4, z4, z4, z4, z4, z4, z4, z4};

#define PHASE(sA_, sB_, VM, ...) do { \
    asm volatile("s_waitcnt vmcnt(" #VM ")" ::: "memory"); \
    __builtin_amdgcn_s_barrier(); \
    __builtin_amdgcn_sched_barrier(0); \
    const u16* pA_ = &cs[sA_][0]; \
    bf16x8 fA0 = *(const bf16x8*)(pA_ + base0); \
    bf16x8 fA1 = *(const bf16x8*)(pA_ + base0 + 1024); \
    bf16x8 fA2 = *(const bf16x8*)(pA_ + base0 + 2048); \
    bf16x8 fA3 = *(const bf16x8*)(pA_ + base0 + 3072); \
    bf16x8 fB0 = *(const bf16x8*)(pA_ + base1); \
    bf16x8 fB1 = *(const bf16x8*)(pA_ + base1 + 1024); \
    bf16x8 fB2 = *(const bf16x8*)(pA_ + base1 + 2048); \
    bf16x8 fB3 = *(const bf16x8*)(pA_ + base1 + 3072); \
    __VA_ARGS__; \
    __builtin_amdgcn_s_setprio(1); \
    sacc[0] = MFMA16(xf[2 * (sA_)],     fA0, sacc[0]); \
    sacc[1] = MFMA16(xf[2 * (sA_)],     fA1, sacc[1]); \
    sacc[2] = MFMA16(xf[2 * (sA_)],     fA2, sacc[2]); \
    sacc[3] = MFMA16(xf[2 * (sA_)],     fA3, sacc[3]); \
    sacc[0] = MFMA16(xf[2 * (sA_) + 1], fB0, sacc[0]); \
    sacc[1] = MFMA16(xf[2 * (sA_) + 1], fB1, sacc[1]); \
    sacc[2] = MFMA16(xf[2 * (sA_) + 1], fB2, sacc[2]); \
    sacc[3] = MFMA16(xf[2 * (sA_) + 1], fB3, sacc[3]); \
    __builtin_amdgcn_s_setprio(0); \
    const u16* pB_ = &cs[sB_][0]; \
    bf16x8 gA0 = *(const bf16x8*)(pB_ + base0); \
    bf16x8 gA1 = *(const bf16x8*)(pB_ + base0 + 1024); \
    bf16x8 gA2 = *(const bf16x8*)(pB_ + base0 + 2048); \
    bf16x8 gA3 = *(const bf16x8*)(pB_ + base0 + 3072); \
    bf16x8 gB0 = *(const bf16x8*)(pB_ + base1); \
    bf16x8 gB1 = *(const bf16x8*)(pB_ + base1 + 1024); \
    bf16x8 gB2 = *(const bf16x8*)(pB_ + base1 + 2048); \
    bf16x8 gB3 = *(const bf16x8*)(pB_ + base1 + 3072); \
    __builtin_amdgcn_s_setprio(1); \
    sacc[0] = MFMA16(xf[2 * (sB_)],     gA0, sacc[0]); \
    sacc[1] = MFMA16(xf[2 * (sB_)],     gA1, sacc[1]); \
    sacc[2] = MFMA16(xf[2 * (sB_)],     gA2, sacc[2]); \
    sacc[3] = MFMA16(xf[2 * (sB_)],     gA3, sacc[3]); \
    sacc[0] = MFMA16(xf[2 * (sB_) + 1], gB0, sacc[0]); \
    sacc[1] = MFMA16(xf[2 * (sB_) + 1], gB1, sacc[1]); \
    sacc[2] = MFMA16(xf[2 * (sB_) + 1], gB2, sacc[2]); \
    sacc[3] = MFMA16(xf[2 * (sB_) + 1], gB3, sacc[3]); \
    __builtin_amdgcn_s_setprio(0); \
  } while (0)

#define TAIL(WS, NC) do { \
    _Pragma("unroll") \
    for (int ct = 0; ct < 4; ++ct) { \
      _Pragma("unroll") \
      for (int r = 0; r < 4; ++r) { \
        const int m_ = mw * 16 + lg * 4 + r; \
        const float v_ = __builtin_amdgcn_exp2f(NB2 * (xq[r] + cq[ct] - 2.f * sacc[ct][r])); \
        pl[m_ * 64 + (((ct * 16) + l15) ^ ((m_ & 7) << 3))] = f2bf(v_); \
      } \
      sacc[ct] = z4; \
    } \
    asm volatile("s_waitcnt lgkmcnt(0)" ::: "memory"); \
    __builtin_amdgcn_s_barrier(); \
    __builtin_amdgcn_sched_barrier(0); \
    const u16* pw_ = &wt[WS][0]; \
    bf16x8 pa0 = *(const bf16x8*)(pl + mw * 1024 + base0); \
    bf16x8 w0 = *(const bf16x8*)(pw_ + base0); \
    bf16x8 w1 = *(const bf16x8*)(pw_ + base0 + 1024); \
    bf16x8 w2 = *(const bf16x8*)(pw_ + base0 + 2048); \
    bf16x8 w3 = *(const bf16x8*)(pw_ + base0 + 3072); \
    bf16x8 w4 = *(const bf16x8*)(pw_ + base0 + 4096); \
    bf16x8 w5 = *(const bf16x8*)(pw_ + base0 + 5120); \
    bf16x8 w6 = *(const bf16x8*)(pw_ + base0 + 6144); \
    bf16x8 w7 = *(const bf16x8*)(pw_ + base0 + 7168); \
    __builtin_amdgcn_s_setprio(1); \
    oa[0] = MFMA16(pa0, w0, oa[0]); \
    oa[1] = MFMA16(pa0, w1, oa[1]); \
    oa[2] = MFMA16(pa0, w2, oa[2]); \
    oa[3] = MFMA16(pa0, w3, oa[3]); \
    oa[4] = MFMA16(pa0, w4, oa[4]); \
    oa[5] = MFMA16(pa0, w5, oa[5]); \
    oa[6] = MFMA16(pa0, w6, oa[6]); \
    oa[7] = MFMA16(pa0, w7, oa[7]); \
    __builtin_amdgcn_s_setprio(0); \
    bf16x8 pa1 = *(const bf16x8*)(pl + mw * 1024 + base1); \
    bf16x8 v0 = *(const bf16x8*)(pw_ + base1); \
    bf16x8 v1 = *(const bf16x8*)(pw_ + base1 + 1024); \
    bf16x8 v2 = *(const bf16x8*)(pw_ + base1 + 2048); \
    bf16x8 v3 = *(const bf16x8*)(pw_ + base1 + 3072); \
    bf16x8 v4 = *(const bf16x8*)(pw_ + base1 + 4096); \
    bf16x8 v5 = *(const bf16x8*)(pw_ + base1 + 5120); \
    bf16x8 v6 = *(const bf16x8*)(pw_ + base1 + 6144); \
    bf16x8 v7 = *(const bf16x8*)(pw_ + base1 + 7168); \
    __builtin_amdgcn_s_setprio(1); \
    oa[0] = MFMA16(pa1, v0, oa[0]); \
    oa[1] = MFMA16(pa1, v1, oa[1]); \
    oa[2] = MFMA16(pa1, v2, oa[2]); \
    oa[3] = MFMA16(pa1, v3, oa[3]); \
    oa[4] = MFMA16(pa1, v4, oa[4]); \
    oa[5] = MFMA16(pa1, v5, oa[5]); \
    oa[6] = MFMA16(pa1, v6, oa[6]); \
    oa[7] = MFMA16(pa1, v7, oa[7]); \
    __builtin_amdgcn_s_setprio(0); \
    _Pragma("unroll") \
    for (int ct = 0; ct < 4; ++ct) cq[ct] = csq_l[(NC) * 64 + ct * 16 + l15]; \
  } while (0)

  // ---- chunk 0 (prologue-fed vmcnt) ----
  PHASE(0, 1, 4, S_CS(0, 4, 4); S_CS(0, 5, 5));
  PHASE(2, 3, 4, S_CS(0, 6, 6); S_CS(0, 7, 7); S_W(1, 1));
  PHASE(4, 5, 4, S_CS(1, 0, 0); S_CS(1, 1, 1));
  PHASE(6, 7, 4, S_CS(1, 2, 2); S_CS(1, 3, 3));
  TAIL(0, 1);

  // ---- steady chunks ----
  for (int cc = 1; cc < 31; ++cc) {
    PHASE(0, 1, 2, S_CS(cc, 4, 4); S_CS(cc, 5, 5));
    PHASE(2, 3, 2, S_CS(cc, 6, 6); S_CS(cc, 7, 7); S_W(cc + 1, (cc + 1) & 1));
    PHASE(4, 5, 4, S_CS(cc + 1, 0, 0); S_CS(cc + 1, 1, 1));
    PHASE(6, 7, 4, S_CS(cc + 1, 2, 2); S_CS(cc + 1, 3, 3));
    TAIL(cc & 1, cc + 1);
  }

  // ---- last chunk (drain) ----
  PHASE(0, 1, 2, S_CS(31, 4, 4); S_CS(31, 5, 5));
  PHASE(2, 3, 2, S_CS(31, 6, 6); S_CS(31, 7, 7));
  PHASE(4, 5, 2, (void)0);
  PHASE(6, 7, 0, (void)0);
  TAIL(1, 31);

  // ---- epilogue: out += partial (bias added by init_out) ----
#pragma unroll
  for (int ot = 0; ot < 8; ++ot) {
    const int o = ot * 16 + l15;
#pragma unroll
    for (int r = 0; r < 4; ++r) {
      const int m = mw * 16 + lg * 4 + r;
      atomicAdd(&out[(r0 + m) * 128 + o], oa[ot][r]);
    }
  }
#undef PHASE
#undef TAIL
#undef S_CS
#undef S_W
}

extern "C" void kernel_launch(void* const* d_in, const int* in_sizes, int n_in,
                              void* d_out, int out_size, void* d_ws, size_t ws_size,
                              hipStream_t stream) {
  (void)in_sizes; (void)n_in; (void)out_size; (void)ws_size;
  const float* x   = (const float*)d_in[0];
  const float* cen = (const float*)d_in[1];
  const float* W   = (const float*)d_in[2];
  const float* b   = (const float*)d_in[3];
  u16* cbf  = (u16*)d_ws;                    // 4096*512 bf16 = 4 MB
  u16* wtg  = cbf + 4096 * 512;              // 128*4096 bf16 = 1 MB
  float* cs = (float*)(wtg + 128 * 4096);    // 4096 f32 = 16 KB
  prep_cen<<<4096, 128, 0, stream>>>(cen, cbf, cs);
  prep_w<<<64, 256, 0, stream>>>(W, wtg);
  init_out<<<2048, 256, 0, stream>>>(b, (float*)d_out);
  rbf_main<<<256, 512, 0, stream>>>(x, cbf, wtg, cs, (float*)d_out);
}